// Round 8
// baseline (222.789 us; speedup 1.0000x reference)
//
#include <hip/hip_runtime.h>
#include <hip/hip_bf16.h>

// Sizes (fixed by the problem)
#define HDIM 512
#define BB 32
#define SS 4096
#define TR 32                  // rows per tile/block
#define NCH (SS/TR)            // 128 chunks per b
#define NBLK (BB*NCH)          // 4096 blocks

typedef __attribute__((ext_vector_type(8))) short short8;   // 8 x bf16
typedef __attribute__((ext_vector_type(4))) float f32x4;

// Workspace layout (bytes)
#define WS_QB    0                        // 32*512*8 = 131072 (packed qb|V float2)
#define WS_WRBF  131072                   // 512*512*2 = 524288 (fragment-major)
#define WS_PM    (131072+524288)          // 4096*4 (16KB region)
#define WS_PD    (WS_PM+16384)            // 4096*4 (16KB region)
#define WS_PU    (WS_PD+16384)            // 4096*512*4 = 8MB

__device__ __forceinline__ unsigned cvt_pk_bf16(float lo, float hi){
  unsigned r;
  asm("v_cvt_pk_bf16_f32 %0, %1, %2" : "=v"(r) : "v"(lo), "v"(hi));
  return r;
}

__device__ __forceinline__ float fast_tanh(float x){
  float e = __expf(2.f * x);
  return 1.f - __fdividef(2.f, 1.f + e);
}

// ---------------- K1: prep (fused) ----------------
// blocks 0..127 : fragment-major bf16 Wr:
//   frag f = (t16*16 + kt)*64 + lane holds Wr[t16*16+(lane&15)][kt*32+(lane>>4)*8 ..+8]
//   -> k_main B-frag load = ONE contiguous 1KB wave load.
// blocks 128..159: qv2[b,h] = { bq[h]+br[h]+query[b,:].Wq[h,:],  V[h] }
__global__ __launch_bounds__(256) void k_prep(const float* __restrict__ Wr,
                                              unsigned short* __restrict__ wrbF,
                                              const float* __restrict__ query,
                                              const float* __restrict__ Wq,
                                              const float* __restrict__ bq,
                                              const float* __restrict__ br,
                                              const float* __restrict__ V,
                                              float* __restrict__ qv2){
  int t = threadIdx.x;
  if (blockIdx.x < 128){
    int gid = blockIdx.x*256 + t;        // [0, 32768)
    int lane = gid & 63;
    int tile = gid >> 6;                 // [0,512): kt = tile&15, t16 = tile>>4
    int kt = tile & 15, t16 = tile >> 4;
    int col = t16*16 + (lane & 15);
    int k0  = kt*32 + (lane >> 4)*8;
    const float* src = Wr + (size_t)col*HDIM + k0;
    f32x4 v0 = *(const f32x4*)(src);
    f32x4 v1 = *(const f32x4*)(src + 4);
    uint4 o;
    o.x = cvt_pk_bf16(v0.x, v0.y);
    o.y = cvt_pk_bf16(v0.z, v0.w);
    o.z = cvt_pk_bf16(v1.x, v1.y);
    o.w = cvt_pk_bf16(v1.z, v1.w);
    *(uint4*)(wrbF + (size_t)gid*8) = o;
  } else {
    __shared__ __align__(16) float sq[HDIM];
    int b = blockIdx.x - 128;
    sq[t] = query[b*HDIM + t];
    sq[t+256] = query[b*HDIM + t + 256];
    __syncthreads();
    const f32x4* sq4 = (const f32x4*)sq;
    for (int hh = 0; hh < 2; ++hh){
      int h = t + hh*256;
      const f32x4* w4 = (const f32x4*)(Wq + (size_t)h*HDIM);
      float acc = bq[h] + br[h];
      #pragma unroll 4
      for (int k = 0; k < HDIM/4; ++k){
        f32x4 w = w4[k]; f32x4 q = sq4[k];
        acc += w.x*q.x + w.y*q.y + w.z*q.z + w.w*q.w;
      }
      qv2[(size_t)b*HDIM*2 + 2*h]     = acc;
      qv2[(size_t)b*HDIM*2 + 2*h + 1] = V[h];
    }
  }
}

// ---------------- K2: main fused kernel ----------------
// 4096 blocks x 256 thr (4 waves), 32-row tile, ~37KB LDS -> 4 blocks/CU.
// A-layout in LDS: element (row,k) at byte row*1024 + (2k ^ ((row&7)<<4)).
// Identity: (kt*64 + g*16) ^ ((row&7)<<4)
//         = (kt ^ bsel)*64 + (g*16 ^ ((row&3)<<4)),  bsel = (row>>2)&1
// -> A ds_reads use two thread-uniform bases (even/odd kt) + imm offsets.
__global__ __launch_bounds__(256, 4) void k_main(const float* __restrict__ ref,
                                                 const unsigned short* __restrict__ wrbF,
                                                 const float* __restrict__ qv2,
                                                 float* __restrict__ pm,
                                                 float* __restrict__ pd,
                                                 float* __restrict__ pu){
  int bid = blockIdx.x;
  int b = bid >> 7;
  int chunk = bid & 127;
  int tid = threadIdx.x;
  int w = tid >> 6, lane = tid & 63;
  int lo16 = lane & 15, g = lane >> 4;

  __shared__ __align__(16) unsigned short sA[TR*HDIM]; // 32KB swizzled bf16
  __shared__ __align__(16) float sQV[HDIM*2];          // packed {qb+br, V}
  __shared__ float sLog[4][TR];
  __shared__ float sE[TR];
  __shared__ float sMD[2];

  // ---- stage A: 32 rows x 512 f32 = 4096 f32x4; 16 per thread ----
  {
    const f32x4* s4 = (const f32x4*)(ref + ((size_t)b*SS + (size_t)chunk*TR)*HDIM) + tid;
    f32x4 R[16];
    #pragma unroll
    for (int i = 0; i < 16; ++i) R[i] = s4[256*i];
    #pragma unroll
    for (int i = 0; i < 16; ++i){
      int idx = tid + 256*i;
      int row = idx >> 7, c4 = idx & 127;
      f32x4 v = R[i];
      uint2 o;
      o.x = cvt_pk_bf16(v.x, v.y);
      o.y = cvt_pk_bf16(v.z, v.w);
      unsigned byte = (unsigned)(row*1024) + (((unsigned)c4*8) ^ ((unsigned)(row & 7) << 4));
      *(uint2*)((char*)sA + byte) = o;
    }
  }
  {
    const float2* src = (const float2*)(qv2 + (size_t)b*HDIM*2);
    float2* dst = (float2*)sQV;
    dst[tid]       = src[tid];
    dst[tid + 256] = src[tid + 256];
  }
  __syncthreads();

  // ---- GEMM + logits: wave covers cols [w*128, w*128+128), rows 0..31 ----
  unsigned baseA = (unsigned)(lo16*1024) + (((unsigned)g*16) ^ ((unsigned)(lo16 & 3) << 4));
  unsigned bsel  = (unsigned)((lo16 >> 2) & 1) * 64u;
  const char* pAe = (const char*)sA + baseA + bsel;        // even kt: + kt*64
  const char* pAo = (const char*)sA + baseA - bsel + 64;   // odd kt:  + (kt-1)*64

  float lacc[2][4];
  #pragma unroll
  for (int m = 0; m < 2; ++m)
    #pragma unroll
    for (int r = 0; r < 4; ++r)
      lacc[m][r] = 0.f;

  #pragma unroll
  for (int nh = 0; nh < 2; ++nh){
    int tbase = w*8 + nh*4;             // t16 tile index base (4 tiles)
    const short8* wfp = (const short8*)wrbF + ((size_t)tbase*16*64 + lane);
    f32x4 acc[2][4];
    #pragma unroll
    for (int m = 0; m < 2; ++m)
      #pragma unroll
      for (int n = 0; n < 4; ++n)
        acc[m][n] = (f32x4){0.f, 0.f, 0.f, 0.f};

    #pragma unroll
    for (int kt = 0; kt < 16; ++kt){
      short8 af[2];
      #pragma unroll
      for (int m = 0; m < 2; ++m){
        if (kt & 1)
          af[m] = *(const short8*)(pAo + (m*16384 + (kt-1)*64));
        else
          af[m] = *(const short8*)(pAe + (m*16384 + kt*64));
      }
      short8 bfr[4];
      #pragma unroll
      for (int n = 0; n < 4; ++n)
        bfr[n] = wfp[(size_t)n*1024 + kt*64];
      #pragma unroll
      for (int m = 0; m < 2; ++m)
        #pragma unroll
        for (int n = 0; n < 4; ++n)
          acc[m][n] = __builtin_amdgcn_mfma_f32_16x16x32_bf16(af[m], bfr[n], acc[m][n], 0, 0, 0);
    }

    // epilogue: D-layout col=lane&15, row=16m+4g+r
    #pragma unroll
    for (int n = 0; n < 4; ++n){
      int col = (tbase + n)*16 + lo16;
      float2 qv = ((const float2*)sQV)[col];
      #pragma unroll
      for (int m = 0; m < 2; ++m)
        #pragma unroll
        for (int r = 0; r < 4; ++r){
          float x = qv.x + acc[m][n][r];
          lacc[m][r] += qv.y * fast_tanh(x);
        }
    }
  }

  // reduce over 16 lanes (cols) -> logits for rows 16m+4g+r
  #pragma unroll
  for (int m = 0; m < 2; ++m)
    #pragma unroll
    for (int r = 0; r < 4; ++r){
      float v = lacc[m][r];
      v += __shfl_xor(v, 1); v += __shfl_xor(v, 2);
      v += __shfl_xor(v, 4); v += __shfl_xor(v, 8);
      lacc[m][r] = v;
    }
  if (lo16 == 0){
    #pragma unroll
    for (int m = 0; m < 2; ++m)
      #pragma unroll
      for (int r = 0; r < 4; ++r)
        sLog[w][16*m + 4*g + r] = lacc[m][r];
  }
  __syncthreads();

  // ---- chunk softmax partials (wave 0, lanes 0..31) ----
  if (w == 0){
    float l = (lane < TR)
      ? (sLog[0][lane] + sLog[1][lane] + sLog[2][lane] + sLog[3][lane])
      : -3.0e38f;
    float mx = l;
    mx = fmaxf(mx, __shfl_xor(mx, 1));  mx = fmaxf(mx, __shfl_xor(mx, 2));
    mx = fmaxf(mx, __shfl_xor(mx, 4));  mx = fmaxf(mx, __shfl_xor(mx, 8));
    mx = fmaxf(mx, __shfl_xor(mx, 16));
    float e = (lane < TR) ? __expf(l - mx) : 0.f;
    float d = e;
    d += __shfl_xor(d, 1); d += __shfl_xor(d, 2); d += __shfl_xor(d, 4);
    d += __shfl_xor(d, 8); d += __shfl_xor(d, 16);
    if (lane < TR) sE[lane] = e;
    if (lane == 0){ sMD[0] = mx; sMD[1] = d; }
  }
  __syncthreads();

  // ---- u[k] = sum_s e_s * A[s,k]  (k = 2*tid, 2*tid+1) ----
  float u0 = 0.f, u1 = 0.f;
  #pragma unroll 8
  for (int s = 0; s < TR; ++s){
    unsigned byte = ((unsigned)(s*1024 + tid*4)) ^ ((unsigned)(s & 7) << 4);
    unsigned pk = *(const unsigned*)((const char*)sA + byte);
    float e = sE[s];
    u0 += e * __uint_as_float((pk & 0xFFFFu) << 16);
    u1 += e * __uint_as_float(pk & 0xFFFF0000u);
  }
  pu[(size_t)bid*HDIM + 2*tid]     = u0;
  pu[(size_t)bid*HDIM + 2*tid + 1] = u1;
  if (tid == 0){ pm[bid] = sMD[0]; pd[bid] = sMD[1]; }
}

// ---------------- K3: combine 128 partials per b + out = Wr @ u + br ----------------
__global__ __launch_bounds__(256) void k_final(const float* __restrict__ Wr,
                                               const float* __restrict__ br,
                                               const float* __restrict__ pm,
                                               const float* __restrict__ pd,
                                               const float* __restrict__ pu,
                                               float* __restrict__ out){
  int b = blockIdx.x, t = threadIdx.x;
  __shared__ float sM[NCH], sD[NCH], sSc[NCH];
  __shared__ __align__(16) float sU[HDIM];
  __shared__ float sMx, sDen;

  if (t < NCH){ sM[t] = pm[b*NCH + t]; sD[t] = pd[b*NCH + t]; }
  __syncthreads();
  if (t < 64){
    float mx = fmaxf(sM[t], sM[t+64]);
    mx = fmaxf(mx, __shfl_xor(mx, 1));  mx = fmaxf(mx, __shfl_xor(mx, 2));
    mx = fmaxf(mx, __shfl_xor(mx, 4));  mx = fmaxf(mx, __shfl_xor(mx, 8));
    mx = fmaxf(mx, __shfl_xor(mx, 16)); mx = fmaxf(mx, __shfl_xor(mx, 32));
    if (t == 0) sMx = mx;
  }
  __syncthreads();
  float mx = sMx;
  if (t < NCH) sSc[t] = __expf(sM[t] - mx);
  __syncthreads();
  if (t < 64){
    float d = sSc[t]*sD[t] + sSc[t+64]*sD[t+64];
    d += __shfl_xor(d, 1); d += __shfl_xor(d, 2); d += __shfl_xor(d, 4);
    d += __shfl_xor(d, 8); d += __shfl_xor(d, 16); d += __shfl_xor(d, 32);
    if (t == 0) sDen = d;
  }
  __syncthreads();

  float inv = 1.f / sDen;
  float u0 = 0.f, u1 = 0.f;
  for (int c = 0; c < NCH; ++c){
    float sc = sSc[c];
    const float* p = pu + ((size_t)(b*NCH + c))*HDIM;
    u0 += sc * p[t];
    u1 += sc * p[t+256];
  }
  sU[t]     = u0 * inv;
  sU[t+256] = u1 * inv;
  __syncthreads();

  const f32x4* su4 = (const f32x4*)sU;
  for (int hh = 0; hh < 2; ++hh){
    int h = t + hh*256;
    const f32x4* w4 = (const f32x4*)(Wr + (size_t)h*HDIM);
    float acc = br[h];
    #pragma unroll 4
    for (int k = 0; k < HDIM/4; ++k){
      f32x4 wv = w4[k], uv = su4[k];
      acc += wv.x*uv.x + wv.y*uv.y + wv.z*uv.z + wv.w*uv.w;
    }
    out[b*HDIM + h] = acc;
  }
}

extern "C" void kernel_launch(void* const* d_in, const int* in_sizes, int n_in,
                              void* d_out, int out_size, void* d_ws, size_t ws_size,
                              hipStream_t stream){
  const float* query = (const float*)d_in[0];
  const float* ref   = (const float*)d_in[1];
  const float* Wq    = (const float*)d_in[2];
  const float* bq    = (const float*)d_in[3];
  const float* Wr    = (const float*)d_in[4];
  const float* br    = (const float*)d_in[5];
  const float* V     = (const float*)d_in[6];
  char* ws = (char*)d_ws;
  float*          qv2  = (float*)(ws + WS_QB);
  unsigned short* wrbF = (unsigned short*)(ws + WS_WRBF);
  float*          pm   = (float*)(ws + WS_PM);
  float*          pd   = (float*)(ws + WS_PD);
  float*          pu   = (float*)(ws + WS_PU);
  float* out = (float*)d_out;

  k_prep<<<dim3(160), dim3(256), 0, stream>>>(Wr, wrbF, query, Wq, bq, br, V, qv2);
  k_main<<<dim3(NBLK), dim3(256), 0, stream>>>(ref, wrbF, qv2, pm, pd, pu);
  k_final<<<dim3(BB), dim3(256), 0, stream>>>(Wr, br, pm, pd, pu, out);
}

// Round 9
// 179.096 us; speedup vs baseline: 1.2440x; 1.2440x over previous
//
#include <hip/hip_runtime.h>
#include <hip/hip_bf16.h>

// Sizes (fixed by the problem)
#define HDIM 512
#define BB 32
#define SS 4096
#define TR 64                  // rows per block
#define NCH (SS/TR)            // 64 chunks per b
#define NBLK (BB*NCH)          // 2048 blocks

typedef __attribute__((ext_vector_type(8))) short short8;   // 8 x bf16
typedef __attribute__((ext_vector_type(4))) float f32x4;

// Workspace layout (bytes)
#define WS_QB    0                        // 32*512*4 = 65536
#define WS_WRBF  65536                    // 512*512*2 = 524288 (fragment-major)
#define WS_PM    (65536+524288)           // 2048*4 (16KB region)
#define WS_PD    (WS_PM+16384)            // 2048*4 (16KB region)
#define WS_PU    (WS_PD+16384)            // 2048*512*4 = 4MB

__device__ __forceinline__ unsigned short f2bf(float f){
  unsigned u = __float_as_uint(f);
  u += 0x7FFFu + ((u >> 16) & 1u);        // RNE
  return (unsigned short)(u >> 16);
}

__device__ __forceinline__ unsigned cvt_pk_bf16(float lo, float hi){
  unsigned r;
  asm("v_cvt_pk_bf16_f32 %0, %1, %2" : "=v"(r) : "v"(lo), "v"(hi));
  return r;
}

__device__ __forceinline__ float fast_tanh(float x){
  float e = __expf(2.f * x);
  return 1.f - __fdividef(2.f, 1.f + e);
}

// ---------------- K1: prep (fused) ----------------
// blocks 0..127 : fragment-major bf16 Wr:
//   frag f = (t16*16 + kt)*64 + lane holds Wr[t16*16+(lane&15)][kt*32+(lane>>4)*8 ..+8]
//   -> k_main B-frag load = ONE contiguous 1KB wave load.
// blocks 128..159: qb[b,h] = bq[h] + br[h] + query[b,:] . Wq[h,:]
__global__ __launch_bounds__(256) void k_prep(const float* __restrict__ Wr,
                                              unsigned short* __restrict__ wrbF,
                                              const float* __restrict__ query,
                                              const float* __restrict__ Wq,
                                              const float* __restrict__ bq,
                                              const float* __restrict__ br,
                                              float* __restrict__ qb){
  int t = threadIdx.x;
  if (blockIdx.x < 128){
    int gid = blockIdx.x*256 + t;        // [0, 32768)
    int lane = gid & 63;
    int tile = gid >> 6;                 // [0,512): kt = tile&15, t16 = tile>>4
    int kt = tile & 15, t16 = tile >> 4;
    int col = t16*16 + (lane & 15);
    int k0  = kt*32 + (lane >> 4)*8;
    const float* src = Wr + (size_t)col*HDIM + k0;
    f32x4 v0 = *(const f32x4*)(src);
    f32x4 v1 = *(const f32x4*)(src + 4);
    uint4 o;
    o.x = cvt_pk_bf16(v0.x, v0.y);
    o.y = cvt_pk_bf16(v0.z, v0.w);
    o.z = cvt_pk_bf16(v1.x, v1.y);
    o.w = cvt_pk_bf16(v1.z, v1.w);
    *(uint4*)(wrbF + (size_t)gid*8) = o;
  } else {
    __shared__ __align__(16) float sq[HDIM];
    int b = blockIdx.x - 128;
    sq[t] = query[b*HDIM + t];
    sq[t+256] = query[b*HDIM + t + 256];
    __syncthreads();
    const f32x4* sq4 = (const f32x4*)sq;
    for (int hh = 0; hh < 2; ++hh){
      int h = t + hh*256;
      const f32x4* w4 = (const f32x4*)(Wq + (size_t)h*HDIM);
      float acc = bq[h] + br[h];
      #pragma unroll 4
      for (int k = 0; k < HDIM/4; ++k){
        f32x4 w = w4[k]; f32x4 q = sq4[k];
        acc += w.x*q.x + w.y*q.y + w.z*q.z + w.w*q.w;
      }
      qb[b*HDIM + h] = acc;
    }
  }
}

// ---------------- K2: main fused kernel ----------------
// 2048 blocks x 512 thr (8 waves), 64-row tile, ~74.5KB LDS -> 2 blocks/CU.
// amdgpu_waves_per_eu(4,4) pins occupancy so the allocator uses the full
// 128-VGPR budget (R7/R8 lesson: default allocator picks 64 and spills).
// Staging in two 8xf32x4 half-passes (peak live ~32 regs) = spill-proof.
__global__ __launch_bounds__(512)
__attribute__((amdgpu_waves_per_eu(4, 4)))
void k_main(const float* __restrict__ ref,
            const unsigned short* __restrict__ wrbF,
            const float* __restrict__ qb,
            const float* __restrict__ V,
            float* __restrict__ pm,
            float* __restrict__ pd,
            float* __restrict__ pu){
  int bid = blockIdx.x;
  int b = bid >> 6;
  int chunk = bid & 63;
  int tid = threadIdx.x;
  int w = tid >> 6, lane = tid & 63;
  int lo16 = lane & 15, g = lane >> 4;

  __shared__ __align__(16) unsigned short sA[TR*HDIM]; // 64KB swizzled bf16
  __shared__ __align__(16) float sQb[HDIM];
  __shared__ __align__(16) float sV[HDIM];
  __shared__ float sLog[8][TR];
  __shared__ float sE[TR];
  __shared__ __align__(16) float sUa[2][HDIM];

  sQb[tid] = qb[b*HDIM + tid];
  sV[tid]  = V[tid];

  // ---- stage A: 64 rows x 512 f32 = 8192 f32x4; two half-passes of 8/thread ----
  {
    const f32x4* s4 = (const f32x4*)(ref + ((size_t)b*SS + (size_t)chunk*TR)*HDIM) + tid;
    #pragma unroll
    for (int p = 0; p < 2; ++p){
      f32x4 R[8];
      #pragma unroll
      for (int i = 0; i < 8; ++i) R[i] = s4[p*4096 + 512*i];
      #pragma unroll
      for (int i = 0; i < 8; ++i){
        int idx = tid + 512*i + p*4096;
        int row = idx >> 7, c4 = idx & 127;
        f32x4 v = R[i];
        ushort4 o;
        o.x = f2bf(v.x); o.y = f2bf(v.y); o.z = f2bf(v.z); o.w = f2bf(v.w);
        unsigned byte = (unsigned)(row*1024) + (((unsigned)c4*8) ^ ((unsigned)(row & 7) << 4));
        *(ushort4*)((char*)sA + byte) = o;
      }
    }
  }
  __syncthreads();

  // ---- GEMM + logits: wave covers cols [w*64, w*64+64), rows 0..63 ----
  float lacc[4][4];
  #pragma unroll
  for (int m = 0; m < 4; ++m)
    #pragma unroll
    for (int r = 0; r < 4; ++r)
      lacc[m][r] = 0.f;

  #pragma unroll
  for (int nh = 0; nh < 2; ++nh){
    int tbase = w*4 + nh*2;             // 2 t16 col-tiles per half
    const short8* wfp = (const short8*)wrbF + ((size_t)tbase*16*64 + lane);
    f32x4 acc[4][2];
    #pragma unroll
    for (int m = 0; m < 4; ++m)
      #pragma unroll
      for (int n = 0; n < 2; ++n)
        acc[m][n] = (f32x4){0.f, 0.f, 0.f, 0.f};

    #pragma unroll 4
    for (int kt = 0; kt < 16; ++kt){
      short8 af[4];
      #pragma unroll
      for (int m = 0; m < 4; ++m){
        int row = 16*m + lo16;
        unsigned byte = (unsigned)(row*1024) + (((unsigned)(kt*64 + g*16)) ^ ((unsigned)(row & 7) << 4));
        af[m] = *(const short8*)((const char*)sA + byte);
      }
      short8 bfr[2];
      bfr[0] = wfp[kt*64];
      bfr[1] = wfp[1024 + kt*64];
      #pragma unroll
      for (int m = 0; m < 4; ++m)
        #pragma unroll
        for (int n = 0; n < 2; ++n)
          acc[m][n] = __builtin_amdgcn_mfma_f32_16x16x32_bf16(af[m], bfr[n], acc[m][n], 0, 0, 0);
    }

    // epilogue: D-layout col=lane&15, row=16m+4g+r
    #pragma unroll
    for (int n = 0; n < 2; ++n){
      int col = (tbase + n)*16 + lo16;
      float qv = sQb[col], vv = sV[col];
      #pragma unroll
      for (int m = 0; m < 4; ++m)
        #pragma unroll
        for (int r = 0; r < 4; ++r){
          float x = qv + acc[m][n][r];
          lacc[m][r] += vv * fast_tanh(x);
        }
    }
  }

  // reduce over 16 lanes (cols) -> logit partials for rows 16m+4g+r
  #pragma unroll
  for (int m = 0; m < 4; ++m)
    #pragma unroll
    for (int r = 0; r < 4; ++r){
      float v = lacc[m][r];
      v += __shfl_xor(v, 1); v += __shfl_xor(v, 2);
      v += __shfl_xor(v, 4); v += __shfl_xor(v, 8);
      lacc[m][r] = v;
    }
  if (lo16 == 0){
    #pragma unroll
    for (int m = 0; m < 4; ++m)
      #pragma unroll
      for (int r = 0; r < 4; ++r)
        sLog[w][16*m + 4*g + r] = lacc[m][r];
  }
  __syncthreads();

  // ---- chunk softmax partials (wave 0; 64 lanes = 64 rows) ----
  if (w == 0){
    float l = sLog[0][lane] + sLog[1][lane] + sLog[2][lane] + sLog[3][lane]
            + sLog[4][lane] + sLog[5][lane] + sLog[6][lane] + sLog[7][lane];
    float mx = l;
    mx = fmaxf(mx, __shfl_xor(mx, 1));  mx = fmaxf(mx, __shfl_xor(mx, 2));
    mx = fmaxf(mx, __shfl_xor(mx, 4));  mx = fmaxf(mx, __shfl_xor(mx, 8));
    mx = fmaxf(mx, __shfl_xor(mx, 16)); mx = fmaxf(mx, __shfl_xor(mx, 32));
    float e = __expf(l - mx);
    float d = e;
    d += __shfl_xor(d, 1); d += __shfl_xor(d, 2); d += __shfl_xor(d, 4);
    d += __shfl_xor(d, 8); d += __shfl_xor(d, 16); d += __shfl_xor(d, 32);
    sE[lane] = e;
    if (lane == 0){ pm[bid] = mx; pd[bid] = d; }
  }
  __syncthreads();

  // ---- u[k] = sum_s e_s * A[s,k]; rows split in halves, k = 2*t8, 2*t8+1 ----
  {
    int h = tid >> 8, t8 = tid & 255;
    const char* sAB = (const char*)sA + (unsigned)h*32768u;  // rows h*32..
    const float* eh = sE + h*32;
    float u0 = 0.f, u1 = 0.f;
    #pragma unroll 8
    for (int s2 = 0; s2 < 32; ++s2){
      unsigned byte = (unsigned)(s2*1024) + (((unsigned)(t8*4)) ^ ((unsigned)(s2 & 7) << 4));
      unsigned pk = *(const unsigned*)(sAB + byte);
      float e = eh[s2];
      u0 += e * __uint_as_float((pk & 0xFFFFu) << 16);
      u1 += e * __uint_as_float(pk & 0xFFFF0000u);
    }
    sUa[h][2*t8]     = u0;
    sUa[h][2*t8 + 1] = u1;
  }
  __syncthreads();
  pu[(size_t)bid*HDIM + tid] = sUa[0][tid] + sUa[1][tid];
}

// ---------------- K3: combine 64 partials per b + out = Wr @ u + br ----------------
__global__ __launch_bounds__(256) void k_final(const float* __restrict__ Wr,
                                               const float* __restrict__ br,
                                               const float* __restrict__ pm,
                                               const float* __restrict__ pd,
                                               const float* __restrict__ pu,
                                               float* __restrict__ out){
  int b = blockIdx.x, t = threadIdx.x, lane = t & 63, w = t >> 6;
  __shared__ float sSc[NCH];
  __shared__ __align__(16) float sU[HDIM];
  __shared__ float sMD0;

  if (w == 0){
    float m = pm[b*NCH + lane];
    float mx = m;
    mx = fmaxf(mx, __shfl_xor(mx, 1));  mx = fmaxf(mx, __shfl_xor(mx, 2));
    mx = fmaxf(mx, __shfl_xor(mx, 4));  mx = fmaxf(mx, __shfl_xor(mx, 8));
    mx = fmaxf(mx, __shfl_xor(mx, 16)); mx = fmaxf(mx, __shfl_xor(mx, 32));
    float sc = __expf(m - mx);
    float d = sc * pd[b*NCH + lane];
    d += __shfl_xor(d, 1); d += __shfl_xor(d, 2); d += __shfl_xor(d, 4);
    d += __shfl_xor(d, 8); d += __shfl_xor(d, 16); d += __shfl_xor(d, 32);
    sSc[lane] = sc;
    if (lane == 0) sMD0 = d;
  }
  __syncthreads();

  float inv = 1.f / sMD0;
  float u0 = 0.f, u1 = 0.f;
  for (int c = 0; c < NCH; ++c){
    float sc = sSc[c];
    const float* p = pu + ((size_t)(b*NCH + c))*HDIM;
    u0 += sc * p[t];
    u1 += sc * p[t+256];
  }
  sU[t]     = u0 * inv;
  sU[t+256] = u1 * inv;
  __syncthreads();

  const f32x4* su4 = (const f32x4*)sU;
  for (int hh = 0; hh < 2; ++hh){
    int h = t + hh*256;
    const f32x4* w4 = (const f32x4*)(Wr + (size_t)h*HDIM);
    float acc = br[h];
    #pragma unroll 4
    for (int k = 0; k < HDIM/4; ++k){
      f32x4 wv = w4[k], uv = su4[k];
      acc += wv.x*uv.x + wv.y*uv.y + wv.z*uv.z + wv.w*uv.w;
    }
    out[b*HDIM + h] = acc;
  }
}

extern "C" void kernel_launch(void* const* d_in, const int* in_sizes, int n_in,
                              void* d_out, int out_size, void* d_ws, size_t ws_size,
                              hipStream_t stream){
  const float* query = (const float*)d_in[0];
  const float* ref   = (const float*)d_in[1];
  const float* Wq    = (const float*)d_in[2];
  const float* bq    = (const float*)d_in[3];
  const float* Wr    = (const float*)d_in[4];
  const float* br    = (const float*)d_in[5];
  const float* V     = (const float*)d_in[6];
  char* ws = (char*)d_ws;
  float*          qbv  = (float*)(ws + WS_QB);
  unsigned short* wrbF = (unsigned short*)(ws + WS_WRBF);
  float*          pm   = (float*)(ws + WS_PM);
  float*          pd   = (float*)(ws + WS_PD);
  float*          pu   = (float*)(ws + WS_PU);
  float* out = (float*)d_out;

  k_prep<<<dim3(160), dim3(256), 0, stream>>>(Wr, wrbF, query, Wq, bq, br, qbv);
  k_main<<<dim3(NBLK), dim3(512), 0, stream>>>(ref, wrbF, qbv, V, pm, pd, pu);
  k_final<<<dim3(BB), dim3(256), 0, stream>>>(Wr, br, pm, pd, pu, out);
}

// Round 10
// 169.515 us; speedup vs baseline: 1.3143x; 1.0565x over previous
//
#include <hip/hip_runtime.h>
#include <hip/hip_bf16.h>

// Sizes (fixed by the problem)
#define HDIM 512
#define BB 32
#define SS 4096
#define TR 64                  // rows per block
#define NCH (SS/TR)            // 64 chunks per b
#define NBLK (BB*NCH)          // 2048 blocks

typedef __attribute__((ext_vector_type(8))) short short8;   // 8 x bf16
typedef __attribute__((ext_vector_type(4))) float f32x4;

// Workspace layout (bytes)
#define WS_QB    0                        // 32*512*4 = 65536
#define WS_WRBF  65536                    // 512*512*2 = 524288 (fragment-major)
#define WS_PM    (65536+524288)           // 2048*4 (16KB region)
#define WS_PD    (WS_PM+16384)            // 2048*4 (16KB region)
#define WS_PU    (WS_PD+16384)            // 2048*512*4 = 4MB

__device__ __forceinline__ unsigned cvt_pk_bf16(float lo, float hi){
  unsigned r;
  asm("v_cvt_pk_bf16_f32 %0, %1, %2" : "=v"(r) : "v"(lo), "v"(hi));
  return r;
}

// ---------------- K1: prep (fused) ----------------
// blocks 0..127 : fragment-major bf16 Wr:
//   frag f = (t16*16 + kt)*64 + lane holds Wr[t16*16+(lane&15)][kt*32+(lane>>4)*8 ..+8]
//   -> k_main B-frag load = ONE contiguous 1KB wave load.
// blocks 128..159: qb[b,h] = bq[h] + br[h] + query[b,:] . Wq[h,:]
__global__ __launch_bounds__(256) void k_prep(const float* __restrict__ Wr,
                                              unsigned short* __restrict__ wrbF,
                                              const float* __restrict__ query,
                                              const float* __restrict__ Wq,
                                              const float* __restrict__ bq,
                                              const float* __restrict__ br,
                                              float* __restrict__ qb){
  int t = threadIdx.x;
  if (blockIdx.x < 128){
    int gid = blockIdx.x*256 + t;        // [0, 32768)
    int lane = gid & 63;
    int tile = gid >> 6;                 // [0,512): kt = tile&15, t16 = tile>>4
    int kt = tile & 15, t16 = tile >> 4;
    int col = t16*16 + (lane & 15);
    int k0  = kt*32 + (lane >> 4)*8;
    const float* src = Wr + (size_t)col*HDIM + k0;
    f32x4 v0 = *(const f32x4*)(src);
    f32x4 v1 = *(const f32x4*)(src + 4);
    uint4 o;
    o.x = cvt_pk_bf16(v0.x, v0.y);
    o.y = cvt_pk_bf16(v0.z, v0.w);
    o.z = cvt_pk_bf16(v1.x, v1.y);
    o.w = cvt_pk_bf16(v1.z, v1.w);
    *(uint4*)(wrbF + (size_t)gid*8) = o;
  } else {
    __shared__ __align__(16) float sq[HDIM];
    int b = blockIdx.x - 128;
    sq[t] = query[b*HDIM + t];
    sq[t+256] = query[b*HDIM + t + 256];
    __syncthreads();
    const f32x4* sq4 = (const f32x4*)sq;
    for (int hh = 0; hh < 2; ++hh){
      int h = t + hh*256;
      const f32x4* w4 = (const f32x4*)(Wq + (size_t)h*HDIM);
      float acc = bq[h] + br[h];
      #pragma unroll 4
      for (int k = 0; k < HDIM/4; ++k){
        f32x4 w = w4[k]; f32x4 q = sq4[k];
        acc += w.x*q.x + w.y*q.y + w.z*q.z + w.w*q.w;
      }
      qb[b*HDIM + h] = acc;
    }
  }
}

// ---------------- K2: main fused kernel ----------------
// 2048 blocks x 512 thr (8 waves), 64-row tile, ~74.5KB LDS -> 2 blocks/CU.
// amdgpu_waves_per_eu(4,4) pins occupancy -> allocator gets full 128-VGPR
// budget (R7/R8 lesson). Staging: two 8xf32x4 half-passes (spill-proof),
// converts via v_cvt_pk_bf16_f32 (1 instr / 2 elems).
// Epilogue: sum_h V*tanh = SV - 2*sum vv*rcp(1+exp2(C*acc+qc)), 5 VALU/elem.
__global__ __launch_bounds__(512)
__attribute__((amdgpu_waves_per_eu(4, 4)))
void k_main(const float* __restrict__ ref,
            const unsigned short* __restrict__ wrbF,
            const float* __restrict__ qb,
            const float* __restrict__ V,
            float* __restrict__ pm,
            float* __restrict__ pd,
            float* __restrict__ pu){
  int bid = blockIdx.x;
  int b = bid >> 6;
  int chunk = bid & 63;
  int tid = threadIdx.x;
  int w = tid >> 6, lane = tid & 63;
  int lo16 = lane & 15, g = lane >> 4;

  __shared__ __align__(16) unsigned short sA[TR*HDIM]; // 64KB swizzled bf16
  __shared__ __align__(16) float sQb[HDIM];
  __shared__ __align__(16) float sV[HDIM];
  __shared__ float sLog[8][TR];
  __shared__ float sE[TR];
  __shared__ __align__(16) float sUa[2][HDIM];

  sQb[tid] = qb[b*HDIM + tid];
  sV[tid]  = V[tid];

  // ---- stage A: 64 rows x 512 f32 = 8192 f32x4; two half-passes of 8/thread ----
  {
    const f32x4* s4 = (const f32x4*)(ref + ((size_t)b*SS + (size_t)chunk*TR)*HDIM) + tid;
    #pragma unroll
    for (int p = 0; p < 2; ++p){
      f32x4 R[8];
      #pragma unroll
      for (int i = 0; i < 8; ++i) R[i] = s4[p*4096 + 512*i];
      #pragma unroll
      for (int i = 0; i < 8; ++i){
        int idx = tid + 512*i + p*4096;
        int row = idx >> 7, c4 = idx & 127;
        f32x4 v = R[i];
        uint2 o;
        o.x = cvt_pk_bf16(v.x, v.y);
        o.y = cvt_pk_bf16(v.z, v.w);
        unsigned byte = (unsigned)(row*1024) + (((unsigned)c4*8) ^ ((unsigned)(row & 7) << 4));
        *(uint2*)((char*)sA + byte) = o;
      }
    }
  }
  __syncthreads();

  // ---- GEMM + logits: wave covers cols [w*64, w*64+64), rows 0..63 ----
  const float C2L2E = 2.8853900817779268f;   // 2*log2(e)
  float lacc[4][4];
  #pragma unroll
  for (int m = 0; m < 4; ++m)
    #pragma unroll
    for (int r = 0; r < 4; ++r)
      lacc[m][r] = 0.f;
  float SV = 0.f;

  #pragma unroll
  for (int nh = 0; nh < 2; ++nh){
    int tbase = w*4 + nh*2;             // 2 t16 col-tiles per half
    const short8* wfp = (const short8*)wrbF + ((size_t)tbase*16*64 + lane);
    f32x4 acc[4][2];
    #pragma unroll
    for (int m = 0; m < 4; ++m)
      #pragma unroll
      for (int n = 0; n < 2; ++n)
        acc[m][n] = (f32x4){0.f, 0.f, 0.f, 0.f};

    #pragma unroll 4
    for (int kt = 0; kt < 16; ++kt){
      short8 af[4];
      #pragma unroll
      for (int m = 0; m < 4; ++m){
        int row = 16*m + lo16;
        unsigned byte = (unsigned)(row*1024) + (((unsigned)(kt*64 + g*16)) ^ ((unsigned)(row & 7) << 4));
        af[m] = *(const short8*)((const char*)sA + byte);
      }
      short8 bfr[2];
      bfr[0] = wfp[kt*64];
      bfr[1] = wfp[1024 + kt*64];
      #pragma unroll
      for (int m = 0; m < 4; ++m)
        #pragma unroll
        for (int n = 0; n < 2; ++n)
          acc[m][n] = __builtin_amdgcn_mfma_f32_16x16x32_bf16(af[m], bfr[n], acc[m][n], 0, 0, 0);
    }

    // epilogue: D-layout col=lane&15, row=16m+4g+r
    // contribution per elem: vv - 2*vv*rcp(1+exp2(C*x)) with x = qb+acc
    #pragma unroll
    for (int n = 0; n < 2; ++n){
      int col = (tbase + n)*16 + lo16;
      float qc  = C2L2E * sQb[col];
      float vv  = sV[col];
      float vv2 = -2.f * vv;
      SV += vv;
      #pragma unroll
      for (int m = 0; m < 4; ++m)
        #pragma unroll
        for (int r = 0; r < 4; ++r){
          float e  = __builtin_amdgcn_exp2f(__builtin_fmaf(C2L2E, acc[m][n][r], qc));
          float rc = __builtin_amdgcn_rcpf(1.f + e);
          lacc[m][r] = __builtin_fmaf(vv2, rc, lacc[m][r]);
        }
    }
  }
  #pragma unroll
  for (int m = 0; m < 4; ++m)
    #pragma unroll
    for (int r = 0; r < 4; ++r)
      lacc[m][r] += SV;

  // reduce over 16 lanes (cols) -> logit partials for rows 16m+4g+r
  #pragma unroll
  for (int m = 0; m < 4; ++m)
    #pragma unroll
    for (int r = 0; r < 4; ++r){
      float v = lacc[m][r];
      v += __shfl_xor(v, 1); v += __shfl_xor(v, 2);
      v += __shfl_xor(v, 4); v += __shfl_xor(v, 8);
      lacc[m][r] = v;
    }
  if (lo16 == 0){
    #pragma unroll
    for (int m = 0; m < 4; ++m)
      #pragma unroll
      for (int r = 0; r < 4; ++r)
        sLog[w][16*m + 4*g + r] = lacc[m][r];
  }
  __syncthreads();

  // ---- chunk softmax partials (wave 0; 64 lanes = 64 rows) ----
  if (w == 0){
    float l = sLog[0][lane] + sLog[1][lane] + sLog[2][lane] + sLog[3][lane]
            + sLog[4][lane] + sLog[5][lane] + sLog[6][lane] + sLog[7][lane];
    float mx = l;
    mx = fmaxf(mx, __shfl_xor(mx, 1));  mx = fmaxf(mx, __shfl_xor(mx, 2));
    mx = fmaxf(mx, __shfl_xor(mx, 4));  mx = fmaxf(mx, __shfl_xor(mx, 8));
    mx = fmaxf(mx, __shfl_xor(mx, 16)); mx = fmaxf(mx, __shfl_xor(mx, 32));
    float e = __expf(l - mx);
    float d = e;
    d += __shfl_xor(d, 1); d += __shfl_xor(d, 2); d += __shfl_xor(d, 4);
    d += __shfl_xor(d, 8); d += __shfl_xor(d, 16); d += __shfl_xor(d, 32);
    sE[lane] = e;
    if (lane == 0){ pm[bid] = mx; pd[bid] = d; }
  }
  __syncthreads();

  // ---- u[k] = sum_s e_s * A[s,k]; rows split in halves, k = 2*t8, 2*t8+1 ----
  {
    int h = tid >> 8, t8 = tid & 255;
    const char* sAB = (const char*)sA + (unsigned)h*32768u;  // rows h*32..
    const float* eh = sE + h*32;
    float u0 = 0.f, u1 = 0.f;
    #pragma unroll 8
    for (int s2 = 0; s2 < 32; ++s2){
      unsigned byte = (unsigned)(s2*1024) + (((unsigned)(t8*4)) ^ ((unsigned)(s2 & 7) << 4));
      unsigned pk = *(const unsigned*)(sAB + byte);
      float e = eh[s2];
      u0 += e * __uint_as_float((pk & 0xFFFFu) << 16);
      u1 += e * __uint_as_float(pk & 0xFFFF0000u);
    }
    sUa[h][2*t8]     = u0;
    sUa[h][2*t8 + 1] = u1;
  }
  __syncthreads();
  pu[(size_t)bid*HDIM + tid] = sUa[0][tid] + sUa[1][tid];
}

// ---------------- K3: combine 64 partials per b + out = Wr @ u + br ----------------
__global__ __launch_bounds__(256) void k_final(const float* __restrict__ Wr,
                                               const float* __restrict__ br,
                                               const float* __restrict__ pm,
                                               const float* __restrict__ pd,
                                               const float* __restrict__ pu,
                                               float* __restrict__ out){
  int b = blockIdx.x, t = threadIdx.x, lane = t & 63, w = t >> 6;
  __shared__ float sSc[NCH];
  __shared__ __align__(16) float sU[HDIM];
  __shared__ float sMD0;

  if (w == 0){
    float m = pm[b*NCH + lane];
    float mx = m;
    mx = fmaxf(mx, __shfl_xor(mx, 1));  mx = fmaxf(mx, __shfl_xor(mx, 2));
    mx = fmaxf(mx, __shfl_xor(mx, 4));  mx = fmaxf(mx, __shfl_xor(mx, 8));
    mx = fmaxf(mx, __shfl_xor(mx, 16)); mx = fmaxf(mx, __shfl_xor(mx, 32));
    float sc = __expf(m - mx);
    float d = sc * pd[b*NCH + lane];
    d += __shfl_xor(d, 1); d += __shfl_xor(d, 2); d += __shfl_xor(d, 4);
    d += __shfl_xor(d, 8); d += __shfl_xor(d, 16); d += __shfl_xor(d, 32);
    sSc[lane] = sc;
    if (lane == 0) sMD0 = d;
  }
  __syncthreads();

  float inv = 1.f / sMD0;
  float u0 = 0.f, u1 = 0.f;
  for (int c = 0; c < NCH; ++c){
    float sc = sSc[c];
    const float* p = pu + ((size_t)(b*NCH + c))*HDIM;
    u0 += sc * p[t];
    u1 += sc * p[t+256];
  }
  sU[t]     = u0 * inv;
  sU[t+256] = u1 * inv;
  __syncthreads();

  const f32x4* su4 = (const f32x4*)sU;
  for (int hh = 0; hh < 2; ++hh){
    int h = t + hh*256;
    const f32x4* w4 = (const f32x4*)(Wr + (size_t)h*HDIM);
    float acc = br[h];
    #pragma unroll 4
    for (int k = 0; k < HDIM/4; ++k){
      f32x4 wv = w4[k], uv = su4[k];
      acc += wv.x*uv.x + wv.y*uv.y + wv.z*uv.z + wv.w*uv.w;
    }
    out[b*HDIM + h] = acc;
  }
}

extern "C" void kernel_launch(void* const* d_in, const int* in_sizes, int n_in,
                              void* d_out, int out_size, void* d_ws, size_t ws_size,
                              hipStream_t stream){
  const float* query = (const float*)d_in[0];
  const float* ref   = (const float*)d_in[1];
  const float* Wq    = (const float*)d_in[2];
  const float* bq    = (const float*)d_in[3];
  const float* Wr    = (const float*)d_in[4];
  const float* br    = (const float*)d_in[5];
  const float* V     = (const float*)d_in[6];
  char* ws = (char*)d_ws;
  float*          qbv  = (float*)(ws + WS_QB);
  unsigned short* wrbF = (unsigned short*)(ws + WS_WRBF);
  float*          pm   = (float*)(ws + WS_PM);
  float*          pd   = (float*)(ws + WS_PD);
  float*          pu   = (float*)(ws + WS_PU);
  float* out = (float*)d_out;

  k_prep<<<dim3(160), dim3(256), 0, stream>>>(Wr, wrbF, query, Wq, bq, br, qbv);
  k_main<<<dim3(NBLK), dim3(512), 0, stream>>>(ref, wrbF, qbv, V, pm, pd, pu);
  k_final<<<dim3(BB), dim3(256), 0, stream>>>(Wr, br, pm, pd, pu, out);
}

// Round 11
// 136.617 us; speedup vs baseline: 1.6308x; 1.2408x over previous
//
#include <hip/hip_runtime.h>
#include <hip/hip_bf16.h>

// Sizes (fixed by the problem)
#define HDIM 512
#define BB 32
#define SS 4096
#define TR 64                  // rows per block
#define NCH (SS/TR)            // 64 chunks per b
#define NBLK (BB*NCH)          // 2048 blocks

typedef __attribute__((ext_vector_type(8))) short short8;   // 8 x bf16
typedef __attribute__((ext_vector_type(4))) float f32x4;

// Workspace layout (bytes)
#define WS_QB    0                        // 32*512*4 = 65536
#define WS_WRBF  65536                    // 512*512*2 = 524288 (fragment-major)
#define WS_PM    (65536+524288)           // 2048*4 (16KB region)
#define WS_PD    (WS_PM+16384)            // 2048*4 (16KB region)
#define WS_PRB   (WS_PD+16384)            // 2048*512*4 = 4MB (r-domain partials)

__device__ __forceinline__ unsigned cvt_pk_bf16(float lo, float hi){
  unsigned r;
  asm("v_cvt_pk_bf16_f32 %0, %1, %2" : "=v"(r) : "v"(lo), "v"(hi));
  return r;
}

// ---------------- K1: prep (fused) ----------------
// blocks 0..127 : fragment-major bf16 Wr:
//   frag f = (t16*16 + kt)*64 + lane holds Wr[t16*16+(lane&15)][kt*32+(lane>>4)*8 ..+8]
//   -> k_main B-frag load = ONE contiguous 1KB wave load.
// blocks 128..159: qb[b,h] = bq[h] + br[h] + query[b,:] . Wq[h,:]
__global__ __launch_bounds__(256) void k_prep(const float* __restrict__ Wr,
                                              unsigned short* __restrict__ wrbF,
                                              const float* __restrict__ query,
                                              const float* __restrict__ Wq,
                                              const float* __restrict__ bq,
                                              const float* __restrict__ br,
                                              float* __restrict__ qb){
  int t = threadIdx.x;
  if (blockIdx.x < 128){
    int gid = blockIdx.x*256 + t;        // [0, 32768)
    int lane = gid & 63;
    int tile = gid >> 6;                 // [0,512): kt = tile&15, t16 = tile>>4
    int kt = tile & 15, t16 = tile >> 4;
    int col = t16*16 + (lane & 15);
    int k0  = kt*32 + (lane >> 4)*8;
    const float* src = Wr + (size_t)col*HDIM + k0;
    f32x4 v0 = *(const f32x4*)(src);
    f32x4 v1 = *(const f32x4*)(src + 4);
    uint4 o;
    o.x = cvt_pk_bf16(v0.x, v0.y);
    o.y = cvt_pk_bf16(v0.z, v0.w);
    o.z = cvt_pk_bf16(v1.x, v1.y);
    o.w = cvt_pk_bf16(v1.z, v1.w);
    *(uint4*)(wrbF + (size_t)gid*8) = o;
  } else {
    __shared__ __align__(16) float sq[HDIM];
    int b = blockIdx.x - 128;
    sq[t] = query[b*HDIM + t];
    sq[t+256] = query[b*HDIM + t + 256];
    __syncthreads();
    const f32x4* sq4 = (const f32x4*)sq;
    for (int hh = 0; hh < 2; ++hh){
      int h = t + hh*256;
      const f32x4* w4 = (const f32x4*)(Wq + (size_t)h*HDIM);
      float acc = bq[h] + br[h];
      #pragma unroll 4
      for (int k = 0; k < HDIM/4; ++k){
        f32x4 w = w4[k]; f32x4 q = sq4[k];
        acc += w.x*q.x + w.y*q.y + w.z*q.z + w.w*q.w;
      }
      qb[b*HDIM + h] = acc;
    }
  }
}

// ---------------- K2: main fused kernel ----------------
// 2048 blocks x 512 thr (8 waves), 64-row tile, ~70KB LDS -> 2 blocks/CU.
// Single-pass GEMM: wave covers cols [w*64, w*64+64) with acc[4][4] -> A tile
// read ONCE per wave. A ds_reads use two uniform bases (R7 identity):
//   (kt*64+g*16)^((row&7)<<4) = (kt^b)*64 + (g*16^((row&3)<<4)), b=(row>>2)&1.
// Output partial computed in r-domain from in-register acc (no u-pass):
//   prb[col] = sum_rows e_row * acc ; out = sc-combine(prb) + br in k_final.
__global__ __launch_bounds__(512)
__attribute__((amdgpu_waves_per_eu(4, 4)))
void k_main(const float* __restrict__ ref,
            const unsigned short* __restrict__ wrbF,
            const float* __restrict__ qb,
            const float* __restrict__ V,
            float* __restrict__ pm,
            float* __restrict__ pd,
            float* __restrict__ prb){
  int bid = blockIdx.x;
  int b = bid >> 6;
  int chunk = bid & 63;
  int tid = threadIdx.x;
  int w = tid >> 6, lane = tid & 63;
  int lo16 = lane & 15, g = lane >> 4;

  __shared__ __align__(16) unsigned short sA[TR*HDIM]; // 64KB swizzled bf16
  __shared__ __align__(16) float sQb[HDIM];
  __shared__ __align__(16) float sV[HDIM];
  __shared__ float sLog[8][TR];
  __shared__ __align__(16) float sE[TR];

  sQb[tid] = qb[b*HDIM + tid];
  sV[tid]  = V[tid];

  // ---- stage A: 64 rows x 512 f32 = 8192 f32x4; two half-passes of 8/thread ----
  {
    const f32x4* s4 = (const f32x4*)(ref + ((size_t)b*SS + (size_t)chunk*TR)*HDIM) + tid;
    #pragma unroll
    for (int p = 0; p < 2; ++p){
      f32x4 R[8];
      #pragma unroll
      for (int i = 0; i < 8; ++i) R[i] = s4[p*4096 + 512*i];
      #pragma unroll
      for (int i = 0; i < 8; ++i){
        int idx = tid + 512*i + p*4096;
        int row = idx >> 7, c4 = idx & 127;
        f32x4 v = R[i];
        uint2 o;
        o.x = cvt_pk_bf16(v.x, v.y);
        o.y = cvt_pk_bf16(v.z, v.w);
        unsigned byte = (unsigned)(row*1024) + (((unsigned)c4*8) ^ ((unsigned)(row & 7) << 4));
        *(uint2*)((char*)sA + byte) = o;
      }
    }
  }
  __syncthreads();

  // ---- GEMM: single pass, wave cols [w*64, w*64+64), rows 0..63 ----
  unsigned baseA = (unsigned)(lo16*1024) + (((unsigned)g*16) ^ ((unsigned)(lo16 & 3) << 4));
  unsigned bsel  = (unsigned)((lo16 >> 2) & 1) * 64u;
  const char* pAe = (const char*)sA + baseA + bsel;        // even kt: + kt*64
  const char* pAo = (const char*)sA + baseA - bsel + 64;   // odd kt:  + (kt-1)*64
  const short8* wfp = (const short8*)wrbF + ((size_t)(w*4)*16*64 + lane);

  f32x4 acc[4][4];
  #pragma unroll
  for (int m = 0; m < 4; ++m)
    #pragma unroll
    for (int n = 0; n < 4; ++n)
      acc[m][n] = (f32x4){0.f, 0.f, 0.f, 0.f};

  #pragma unroll 4
  for (int kt = 0; kt < 16; ++kt){
    short8 af[4];
    #pragma unroll
    for (int m = 0; m < 4; ++m){
      if (kt & 1)
        af[m] = *(const short8*)(pAo + (m*16384 + (kt-1)*64));
      else
        af[m] = *(const short8*)(pAe + (m*16384 + kt*64));
    }
    short8 bfr[4];
    #pragma unroll
    for (int n = 0; n < 4; ++n)
      bfr[n] = wfp[(size_t)n*1024 + kt*64];
    #pragma unroll
    for (int m = 0; m < 4; ++m)
      #pragma unroll
      for (int n = 0; n < 4; ++n)
        acc[m][n] = __builtin_amdgcn_mfma_f32_16x16x32_bf16(af[m], bfr[n], acc[m][n], 0, 0, 0);
  }

  // ---- logits epilogue: D-layout col=w*64+n*16+(lane&15), row=16m+4g+r ----
  // per elem: vv - 2*vv*rcp(1+exp2(C*x)), x = qb+acc  (qb folds bq+br)
  const float C2L2E = 2.8853900817779268f;   // 2*log2(e)
  float lacc[4][4];
  #pragma unroll
  for (int m = 0; m < 4; ++m)
    #pragma unroll
    for (int r = 0; r < 4; ++r)
      lacc[m][r] = 0.f;
  float SV = 0.f;

  #pragma unroll
  for (int n = 0; n < 4; ++n){
    int col = w*64 + n*16 + lo16;
    float qc  = C2L2E * sQb[col];
    float vv  = sV[col];
    float vv2 = -2.f * vv;
    SV += vv;
    #pragma unroll
    for (int m = 0; m < 4; ++m)
      #pragma unroll
      for (int r = 0; r < 4; ++r){
        float e  = __builtin_amdgcn_exp2f(__builtin_fmaf(C2L2E, acc[m][n][r], qc));
        float rc = __builtin_amdgcn_rcpf(1.f + e);
        lacc[m][r] = __builtin_fmaf(vv2, rc, lacc[m][r]);
      }
  }
  #pragma unroll
  for (int m = 0; m < 4; ++m)
    #pragma unroll
    for (int r = 0; r < 4; ++r)
      lacc[m][r] += SV;

  // reduce over 16 lanes (cols) -> logit partials for rows 16m+4g+r
  #pragma unroll
  for (int m = 0; m < 4; ++m)
    #pragma unroll
    for (int r = 0; r < 4; ++r){
      float v = lacc[m][r];
      v += __shfl_xor(v, 1); v += __shfl_xor(v, 2);
      v += __shfl_xor(v, 4); v += __shfl_xor(v, 8);
      lacc[m][r] = v;
    }
  if (lo16 == 0){
    #pragma unroll
    for (int m = 0; m < 4; ++m)
      #pragma unroll
      for (int r = 0; r < 4; ++r)
        sLog[w][16*m + 4*g + r] = lacc[m][r];
  }
  __syncthreads();

  // ---- chunk softmax partials (wave 0; 64 lanes = 64 rows) ----
  if (w == 0){
    float l = sLog[0][lane] + sLog[1][lane] + sLog[2][lane] + sLog[3][lane]
            + sLog[4][lane] + sLog[5][lane] + sLog[6][lane] + sLog[7][lane];
    float mx = l;
    mx = fmaxf(mx, __shfl_xor(mx, 1));  mx = fmaxf(mx, __shfl_xor(mx, 2));
    mx = fmaxf(mx, __shfl_xor(mx, 4));  mx = fmaxf(mx, __shfl_xor(mx, 8));
    mx = fmaxf(mx, __shfl_xor(mx, 16)); mx = fmaxf(mx, __shfl_xor(mx, 32));
    float e = __expf(l - mx);
    float d = e;
    d += __shfl_xor(d, 1); d += __shfl_xor(d, 2); d += __shfl_xor(d, 4);
    d += __shfl_xor(d, 8); d += __shfl_xor(d, 16); d += __shfl_xor(d, 32);
    sE[lane] = e;
    if (lane == 0){ pm[bid] = mx; pd[bid] = d; }
  }
  __syncthreads();

  // ---- r-domain partial from in-register acc: prb[col] = sum_rows e*acc ----
  {
    f32x4 e4[4];
    #pragma unroll
    for (int m = 0; m < 4; ++m)
      e4[m] = *(const f32x4*)&sE[16*m + 4*g];     // rows 16m+4g+0..3
    #pragma unroll
    for (int n = 0; n < 4; ++n){
      float rb = 0.f;
      #pragma unroll
      for (int m = 0; m < 4; ++m)
        #pragma unroll
        for (int r = 0; r < 4; ++r)
          rb = __builtin_fmaf(e4[m][r], acc[m][n][r], rb);
      rb += __shfl_xor(rb, 16);
      rb += __shfl_xor(rb, 32);     // fold the 4 g-groups (rows)
      if (g == 0)
        prb[(size_t)bid*HDIM + w*64 + n*16 + lo16] = rb;
    }
  }
}

// ---------------- K3: combine 64 r-domain partials per b, add br ----------------
__global__ __launch_bounds__(256) void k_final(const float* __restrict__ br,
                                               const float* __restrict__ pm,
                                               const float* __restrict__ pd,
                                               const float* __restrict__ prb,
                                               float* __restrict__ out){
  int b = blockIdx.x, t = threadIdx.x, lane = t & 63, w = t >> 6;
  __shared__ float sSc[NCH];
  __shared__ float sMD0;

  if (w == 0){
    float m = pm[b*NCH + lane];
    float mx = m;
    mx = fmaxf(mx, __shfl_xor(mx, 1));  mx = fmaxf(mx, __shfl_xor(mx, 2));
    mx = fmaxf(mx, __shfl_xor(mx, 4));  mx = fmaxf(mx, __shfl_xor(mx, 8));
    mx = fmaxf(mx, __shfl_xor(mx, 16)); mx = fmaxf(mx, __shfl_xor(mx, 32));
    float sc = __expf(m - mx);
    float d = sc * pd[b*NCH + lane];
    d += __shfl_xor(d, 1); d += __shfl_xor(d, 2); d += __shfl_xor(d, 4);
    d += __shfl_xor(d, 8); d += __shfl_xor(d, 16); d += __shfl_xor(d, 32);
    sSc[lane] = sc;
    if (lane == 0) sMD0 = d;
  }
  __syncthreads();

  float inv = 1.f / sMD0;
  float u0 = 0.f, u1 = 0.f;
  for (int c = 0; c < NCH; ++c){
    float sc = sSc[c];
    const float* p = prb + ((size_t)(b*NCH + c))*HDIM;
    u0 += sc * p[t];
    u1 += sc * p[t+256];
  }
  out[b*HDIM + t]       = u0 * inv + br[t];
  out[b*HDIM + t + 256] = u1 * inv + br[t + 256];
}

extern "C" void kernel_launch(void* const* d_in, const int* in_sizes, int n_in,
                              void* d_out, int out_size, void* d_ws, size_t ws_size,
                              hipStream_t stream){
  const float* query = (const float*)d_in[0];
  const float* ref   = (const float*)d_in[1];
  const float* Wq    = (const float*)d_in[2];
  const float* bq    = (const float*)d_in[3];
  const float* Wr    = (const float*)d_in[4];
  const float* br    = (const float*)d_in[5];
  const float* V     = (const float*)d_in[6];
  char* ws = (char*)d_ws;
  float*          qbv  = (float*)(ws + WS_QB);
  unsigned short* wrbF = (unsigned short*)(ws + WS_WRBF);
  float*          pm   = (float*)(ws + WS_PM);
  float*          pd   = (float*)(ws + WS_PD);
  float*          prb  = (float*)(ws + WS_PRB);
  float* out = (float*)d_out;

  k_prep<<<dim3(160), dim3(256), 0, stream>>>(Wr, wrbF, query, Wq, bq, br, qbv);
  k_main<<<dim3(NBLK), dim3(512), 0, stream>>>(ref, wrbF, qbv, V, pm, pd, prb);
  k_final<<<dim3(BB), dim3(256), 0, stream>>>(br, pm, pd, prb, out);
}